// Round 3
// baseline (224.361 us; speedup 1.0000x reference)
//
#include <hip/hip_runtime.h>

using bf16   = __bf16;
using bf16x4 = __bf16 __attribute__((ext_vector_type(4)));
using bf16x8 = __bf16 __attribute__((ext_vector_type(8)));
using f32x4  = float __attribute__((ext_vector_type(4)));
using f32x16 = float __attribute__((ext_vector_type(16)));
using u32x2  = unsigned int __attribute__((ext_vector_type(2)));
using u32x4  = unsigned int __attribute__((ext_vector_type(4)));

#define L_SEQ  2048
#define DMODEL 2048
#define NQH    32
#define NKVH   8
#define HDIM   64
#define QKV_N  3072   // NQH*HDIM + 2*NKVH*HDIM

// ---------- helpers ----------
__device__ __forceinline__ void gload_lds16(const void* g, void* lds) {
  __builtin_amdgcn_global_load_lds((__attribute__((address_space(1))) void*)(g),
                                   (__attribute__((address_space(3))) void*)(lds),
                                   16, 0, 0);
}

__device__ __forceinline__ unsigned pack2(float a, float b) {
  union { bf16 h[2]; unsigned u; } x;
  x.h[0] = (bf16)a; x.h[1] = (bf16)b;
  return x.u;
}

// ---------- fp32 -> bf16 convert ----------
__global__ void cvt_f32_bf16(const float* __restrict__ in, bf16* __restrict__ out, long n) {
  const long stride = (long)gridDim.x * blockDim.x;
  const long n4 = n >> 2;
  for (long i = (long)blockIdx.x * blockDim.x + threadIdx.x; i < n4; i += stride) {
    const float4 v = reinterpret_cast<const float4*>(in)[i];
    bf16x4 o = { (bf16)v.x, (bf16)v.y, (bf16)v.z, (bf16)v.w };
    reinterpret_cast<bf16x4*>(out)[i] = o;
  }
}

// ---------- bf16 GEMM: C(MxN) = A(MxK) * B(NxK)^T, 128x128 tile, BK=64 ----------
// 2-phase double-buffered: issue STAGE(t+1) before computing t, one barrier/iter.
template <typename OutT>
__global__ __launch_bounds__(256)
void gemm_bt(const bf16* __restrict__ A, const bf16* __restrict__ B,
             OutT* __restrict__ C, int M, int N, int K) {
  __shared__ bf16 As[2][128 * 64];
  __shared__ bf16 Bs[2][128 * 64];
  const int tid = threadIdx.x;
  const int w = tid >> 6, l = tid & 63;
  const int wr = w >> 1, wc = w & 1;
  const int lq = l & 15, lg = l >> 4;
  const long m0 = (long)blockIdx.y * 128;
  const long n0 = (long)blockIdx.x * 128;

  const int lrow = l >> 3;
  const int scol = ((l & 7) ^ lrow) << 3;   // swizzled element column within BK

  f32x4 acc[4][4];
#pragma unroll
  for (int i = 0; i < 4; ++i)
#pragma unroll
    for (int j = 0; j < 4; ++j) acc[i][j] = f32x4{0.f, 0.f, 0.f, 0.f};

  // prologue: stage tile 0 into buf 0
#pragma unroll
  for (int i = 0; i < 4; ++i) {
    const int r0 = (w * 4 + i) * 8;
    gload_lds16(A + (m0 + r0 + lrow) * (long)K + scol, &As[0][r0 * 64]);
    gload_lds16(B + (n0 + r0 + lrow) * (long)K + scol, &Bs[0][r0 * 64]);
  }
  __syncthreads();

  const int nk = K >> 6;
  for (int t = 0; t < nk; ++t) {
    const int cur = t & 1, nxt = cur ^ 1;
    // issue next-tile stage (clamped redundant reload on last iter, branchless)
    const int k1 = (t + 1 < nk) ? (t + 1) * 64 : t * 64;
#pragma unroll
    for (int i = 0; i < 4; ++i) {
      const int r0 = (w * 4 + i) * 8;
      gload_lds16(A + (m0 + r0 + lrow) * (long)K + k1 + scol, &As[nxt][r0 * 64]);
      gload_lds16(B + (n0 + r0 + lrow) * (long)K + k1 + scol, &Bs[nxt][r0 * 64]);
    }
    // compute current tile while next-tile loads are in flight
#pragma unroll
    for (int kk = 0; kk < 2; ++kk) {
      bf16x8 af[4], bfr[4];
#pragma unroll
      for (int tt = 0; tt < 4; ++tt) {
        const int rowA = wr * 64 + tt * 16 + lq;
        const int blkA = (kk * 4 + lg) ^ (rowA & 7);
        af[tt] = *reinterpret_cast<const bf16x8*>(&As[cur][rowA * 64 + blkA * 8]);
        const int rowB = wc * 64 + tt * 16 + lq;
        const int blkB = (kk * 4 + lg) ^ (rowB & 7);
        bfr[tt] = *reinterpret_cast<const bf16x8*>(&Bs[cur][rowB * 64 + blkB * 8]);
      }
#pragma unroll
      for (int mt = 0; mt < 4; ++mt)
#pragma unroll
        for (int nt = 0; nt < 4; ++nt)
          acc[mt][nt] = __builtin_amdgcn_mfma_f32_16x16x32_bf16(af[mt], bfr[nt], acc[mt][nt], 0, 0, 0);
    }
    __syncthreads();   // drains next-tile loads (overlapped with the MFMAs above)
  }

#pragma unroll
  for (int mt = 0; mt < 4; ++mt)
#pragma unroll
    for (int r = 0; r < 4; ++r) {
      const long row = m0 + wr * 64 + mt * 16 + lg * 4 + r;
#pragma unroll
      for (int nt = 0; nt < 4; ++nt) {
        const long col = n0 + wc * 64 + nt * 16 + lq;
        C[row * (long)N + col] = (OutT)acc[mt][nt][r];
      }
    }
}

// ---------- RoPE + RMSNorm for Q and K ----------
// Q scaled by SCALE*log2(e) = 0.125*1.442695 so attention works in exp2 domain.
__global__ __launch_bounds__(256)
void rope_rms(const bf16* __restrict__ qkv, const float* __restrict__ qg,
              const float* __restrict__ kg, bf16* __restrict__ qo, bf16* __restrict__ ko) {
  const int gid = blockIdx.x * 4 + (threadIdx.x >> 6);
  const int lane = threadIdx.x & 63;
  const int pos = gid / 40;
  const int hh = gid % 40;            // 0..31 q heads, 32..39 k heads
  const bool isq = hh < 32;
  const int col = isq ? hh * HDIM : NQH * HDIM + (hh - 32) * HDIM;

  float x = (float)qkv[(long)pos * QKV_N + col + lane];
  float p = __shfl_xor(x, 1);
  const float fi = (float)(lane & ~1) * (1.0f / 64.0f);
  const float inv = powf(50000.0f, -fi);
  const float ang = (float)pos * inv;
  const float sn = sinf(ang), cs = cosf(ang);
  const float r = (lane & 1) ? (p * sn + x * cs) : (x * cs - p * sn);

  float ss = r * r;
#pragma unroll
  for (int off = 1; off < 64; off <<= 1) ss += __shfl_xor(ss, off);
  const float scl = rsqrtf(ss * (1.0f / 64.0f) + 1e-5f);
  const float g = isq ? qg[lane] : kg[lane];
  const float o = r * scl * g;

  if (isq) qo[(long)pos * DMODEL + hh * HDIM + lane] = (bf16)(o * 0.18033688011112042f);
  else     ko[(long)pos * (NKVH * HDIM) + (hh - 32) * HDIM + lane] = (bf16)o;
}

// ---------- V transpose: qkv cols [2560,3072) -> vt[h][d][l] ----------
__global__ __launch_bounds__(256)
void vtrans(const bf16* __restrict__ qkv, bf16* __restrict__ vt) {
  __shared__ bf16 t[64][72];
  const int hh = blockIdx.x >> 5;
  const int l0 = (blockIdx.x & 31) * 64;
  const int r = threadIdx.x >> 2;            // 0..63
  const int c = (threadIdx.x & 3) * 16;      // 0,16,32,48

  const bf16* g = qkv + (long)(l0 + r) * QKV_N + (NQH * HDIM + NKVH * HDIM) + hh * HDIM + c;
  u32x4 u0 = reinterpret_cast<const u32x4*>(g)[0];
  u32x4 u1 = reinterpret_cast<const u32x4*>(g)[1];
  bf16* dst = &t[r][c];
  reinterpret_cast<u32x2*>(dst)[0] = u32x2{u0.x, u0.y};
  reinterpret_cast<u32x2*>(dst)[1] = u32x2{u0.z, u0.w};
  reinterpret_cast<u32x2*>(dst)[2] = u32x2{u1.x, u1.y};
  reinterpret_cast<u32x2*>(dst)[3] = u32x2{u1.z, u1.w};
  __syncthreads();

  union { bf16 b[8]; u32x4 u; } o0, o1;
#pragma unroll
  for (int j = 0; j < 8; ++j) { o0.b[j] = t[c + j][r]; o1.b[j] = t[c + 8 + j][r]; }
  bf16* od = vt + ((long)hh * HDIM + r) * L_SEQ + l0 + c;
  reinterpret_cast<u32x4*>(od)[0] = o0.u;
  reinterpret_cast<u32x4*>(od)[1] = o1.u;
}

// ---------- flash attention (causal, GQA), wave-independent, no LDS ----------
// Per wave: 32 q-rows of one head. Swapped MFMAs keep q lane-local.
// Register-pipelined: next-iter K fragments prefetched during current compute;
// V loads issued at iteration top (softmax covers their latency).
__global__ __launch_bounds__(256)
void flash_attn(const bf16* __restrict__ Q, const bf16* __restrict__ Kg,
                const bf16* __restrict__ Vt, bf16* __restrict__ Og) {
  const int w = threadIdx.x >> 6, l = threadIdx.x & 63;
  const int lane31 = l & 31, hi = l >> 5;
  const int wg = blockIdx.x * 4 + w;
  const int h = wg & 31;                 // 4 heads per block share kvh + key range
  const int qi = 63 - (wg >> 5);         // heavy q-tiles dispatched first
  const int kvh = h >> 2;
  const int q0 = qi * 32;
  const int q_abs = q0 + lane31;

  // Q fragments (B-frag of ST): lane -> Q[q0+lane31][c*16 + hi*8 + e]
  const bf16* qrow = Q + (long)q_abs * DMODEL + h * HDIM + hi * 8;
  bf16x8 qf[4];
#pragma unroll
  for (int c = 0; c < 4; ++c) qf[c] = *reinterpret_cast<const bf16x8*>(qrow + c * 16);

  f32x16 o0, o1;
#pragma unroll
  for (int r = 0; r < 16; ++r) { o0[r] = 0.f; o1[r] = 0.f; }
  float m = -3.0e38f, lsum = 0.f;

  const bf16* kbase  = Kg + kvh * HDIM + hi * 8;
  const bf16* v0base = Vt + ((long)(kvh * HDIM + lane31)) * L_SEQ + hi * 8;

  const int nst = qi + 1;                // 32-key subtiles

  // prologue: K fragments for subtile 0
  bf16x8 kc0, kc1, kc2, kc3;
  {
    const bf16* kp = kbase + (long)lane31 * (NKVH * HDIM);
    kc0 = *reinterpret_cast<const bf16x8*>(kp);
    kc1 = *reinterpret_cast<const bf16x8*>(kp + 16);
    kc2 = *reinterpret_cast<const bf16x8*>(kp + 32);
    kc3 = *reinterpret_cast<const bf16x8*>(kp + 48);
  }

  for (int sti = 0; sti < nst; ++sti) {
    const int kb0 = sti * 32;

    // issue V loads for THIS iter early (consumed after softmax)
    const bf16x8 va0 = *reinterpret_cast<const bf16x8*>(v0base + kb0);
    const bf16x8 vb0 = *reinterpret_cast<const bf16x8*>(v0base + 32 * (long)L_SEQ + kb0);
    const bf16x8 va1 = *reinterpret_cast<const bf16x8*>(v0base + kb0 + 16);
    const bf16x8 vb1 = *reinterpret_cast<const bf16x8*>(v0base + 32 * (long)L_SEQ + kb0 + 16);

    // issue NEXT iter's K loads (clamped, branchless — stay in flight across compute)
    const long knrow = (sti + 1 < nst) ? (long)(kb0 + 32 + lane31) : (long)lane31;
    const bf16* kp = kbase + knrow * (NKVH * HDIM);
    const bf16x8 kn0 = *reinterpret_cast<const bf16x8*>(kp);
    const bf16x8 kn1 = *reinterpret_cast<const bf16x8*>(kp + 16);
    const bf16x8 kn2 = *reinterpret_cast<const bf16x8*>(kp + 32);
    const bf16x8 kn3 = *reinterpret_cast<const bf16x8*>(kp + 48);

    // ---- ST = K * Q^T over 4 d-chunks (uses prefetched kc*) ----
    f32x16 st;
#pragma unroll
    for (int r = 0; r < 16; ++r) st[r] = 0.f;
    st = __builtin_amdgcn_mfma_f32_32x32x16_bf16(kc0, qf[0], st, 0, 0, 0);
    st = __builtin_amdgcn_mfma_f32_32x32x16_bf16(kc1, qf[1], st, 0, 0, 0);
    st = __builtin_amdgcn_mfma_f32_32x32x16_bf16(kc2, qf[2], st, 0, 0, 0);
    st = __builtin_amdgcn_mfma_f32_32x32x16_bf16(kc3, qf[3], st, 0, 0, 0);

    // ---- causal mask (diagonal region only) ----
    if (kb0 + 31 > q0) {
#pragma unroll
      for (int r = 0; r < 16; ++r) {
        const int k_abs = kb0 + (r & 3) + 8 * (r >> 2) + 4 * hi;
        if (k_abs > q_abs) st[r] = -3.0e38f;
      }
    }

    // ---- online softmax (base-2 domain; scale folded into Q) ----
    float mx = st[0];
#pragma unroll
    for (int r = 1; r < 16; ++r) mx = fmaxf(mx, st[r]);
    mx = fmaxf(mx, __shfl_xor(mx, 32));
    if (!__all(mx - m <= 8.0f)) {        // defer-max, THR=8
      const float mn = fmaxf(m, mx);
      const float al = __builtin_amdgcn_exp2f(m - mn);
      m = mn; lsum *= al;
#pragma unroll
      for (int r = 0; r < 16; ++r) { o0[r] *= al; o1[r] *= al; }
    }
    float p[16];
    float rs = 0.f;
#pragma unroll
    for (int r = 0; r < 16; ++r) { p[r] = __builtin_amdgcn_exp2f(st[r] - m); rs += p[r]; }
    rs += __shfl_xor(rs, 32);
    lsum += rs;

    // ---- PV: per 16-k slice, assemble P frag in-register, 2 d-tiles ----
    {
      const unsigned W0 = pack2(p[0], p[1]);
      const unsigned W1 = pack2(p[2], p[3]);
      const unsigned W2 = pack2(p[4], p[5]);
      const unsigned W3 = pack2(p[6], p[7]);
      const unsigned X0 = (unsigned)__shfl_xor((int)W0, 32);
      const unsigned X1 = (unsigned)__shfl_xor((int)W1, 32);
      const unsigned X2 = (unsigned)__shfl_xor((int)W2, 32);
      const unsigned X3 = (unsigned)__shfl_xor((int)W3, 32);
      const u32x4 pw = { hi ? X2 : W0, hi ? X3 : W1, hi ? W2 : X0, hi ? W3 : X1 };
      const bf16x8 pf = __builtin_bit_cast(bf16x8, pw);
      o0 = __builtin_amdgcn_mfma_f32_32x32x16_bf16(va0, pf, o0, 0, 0, 0);
      o1 = __builtin_amdgcn_mfma_f32_32x32x16_bf16(vb0, pf, o1, 0, 0, 0);
    }
    {
      const unsigned W0 = pack2(p[8], p[9]);
      const unsigned W1 = pack2(p[10], p[11]);
      const unsigned W2 = pack2(p[12], p[13]);
      const unsigned W3 = pack2(p[14], p[15]);
      const unsigned X0 = (unsigned)__shfl_xor((int)W0, 32);
      const unsigned X1 = (unsigned)__shfl_xor((int)W1, 32);
      const unsigned X2 = (unsigned)__shfl_xor((int)W2, 32);
      const unsigned X3 = (unsigned)__shfl_xor((int)W3, 32);
      const u32x4 pw = { hi ? X2 : W0, hi ? X3 : W1, hi ? W2 : X0, hi ? W3 : X1 };
      const bf16x8 pf = __builtin_bit_cast(bf16x8, pw);
      o0 = __builtin_amdgcn_mfma_f32_32x32x16_bf16(va1, pf, o0, 0, 0, 0);
      o1 = __builtin_amdgcn_mfma_f32_32x32x16_bf16(vb1, pf, o1, 0, 0, 0);
    }

    kc0 = kn0; kc1 = kn1; kc2 = kn2; kc3 = kn3;
  }

  // ---- normalize + store: lane owns q-row, regs span d ----
  const float rl = 1.0f / lsum;
  bf16* orow = Og + (long)q_abs * DMODEL + h * HDIM;
#pragma unroll
  for (int g = 0; g < 4; ++g) {
    const int d0 = 8 * g + 4 * hi;
    u32x2 s0 = { pack2(o0[4 * g + 0] * rl, o0[4 * g + 1] * rl),
                 pack2(o0[4 * g + 2] * rl, o0[4 * g + 3] * rl) };
    u32x2 s1 = { pack2(o1[4 * g + 0] * rl, o1[4 * g + 1] * rl),
                 pack2(o1[4 * g + 2] * rl, o1[4 * g + 3] * rl) };
    *reinterpret_cast<u32x2*>(orow + d0) = s0;
    *reinterpret_cast<u32x2*>(orow + 32 + d0) = s1;
  }
}

// ---------- launch ----------
extern "C" void kernel_launch(void* const* d_in, const int* in_sizes, int n_in,
                              void* d_out, int out_size, void* d_ws, size_t ws_size,
                              hipStream_t stream) {
  const float* x       = (const float*)d_in[0];
  const float* w_qkv   = (const float*)d_in[1];
  const float* w_out   = (const float*)d_in[2];
  const float* q_gamma = (const float*)d_in[3];
  const float* k_gamma = (const float*)d_in[4];
  // d_in[5] = mask (causal tril) — implemented analytically.

  char* ws = (char*)d_ws;
  bf16* xb  = (bf16*)(ws);                       //  8 MiB  x bf16
  bf16* wqb = (bf16*)(ws + (8ul  << 20));        // 12 MiB  w_qkv bf16
  bf16* wob = (bf16*)(ws + (20ul << 20));        //  8 MiB  w_out bf16
  bf16* qkv = (bf16*)(ws + (28ul << 20));        // 12 MiB  qkv bf16
  bf16* qb  = (bf16*)(ws + (40ul << 20));        //  8 MiB  roped/normed Q (pre-scaled)
  bf16* kb  = (bf16*)(ws + (48ul << 20));        //  2 MiB  roped/normed K
  bf16* vt  = (bf16*)(ws + (50ul << 20));        //  2 MiB  V^T
  bf16* ao  = (bf16*)(ws + (52ul << 20));        //  8 MiB  attention out
  float* out = (float*)d_out;

  cvt_f32_bf16<<<2048, 256, 0, stream>>>(x, xb, (long)L_SEQ * DMODEL);
  cvt_f32_bf16<<<2048, 256, 0, stream>>>(w_qkv, wqb, (long)QKV_N * DMODEL);
  cvt_f32_bf16<<<2048, 256, 0, stream>>>(w_out, wob, (long)DMODEL * DMODEL);

  gemm_bt<bf16><<<dim3(QKV_N / 128, L_SEQ / 128), 256, 0, stream>>>(xb, wqb, qkv, L_SEQ, QKV_N, DMODEL);

  rope_rms<<<(L_SEQ * 40) / 4, 256, 0, stream>>>(qkv, q_gamma, k_gamma, qb, kb);
  vtrans<<<NKVH * (L_SEQ / 64), 256, 0, stream>>>(qkv, vt);

  flash_attn<<<(NQH * (L_SEQ / 32)) / 4, 256, 0, stream>>>(qb, kb, vt, ao);

  gemm_bt<float><<<dim3(DMODEL / 128, L_SEQ / 128), 256, 0, stream>>>(ao, wob, out, L_SEQ, DMODEL, DMODEL);
}

// Round 4
// 177.931 us; speedup vs baseline: 1.2609x; 1.2609x over previous
//
#include <hip/hip_runtime.h>

using bf16   = __bf16;
using bf16x4 = __bf16 __attribute__((ext_vector_type(4)));
using bf16x8 = __bf16 __attribute__((ext_vector_type(8)));
using f32x4  = float __attribute__((ext_vector_type(4)));
using f32x16 = float __attribute__((ext_vector_type(16)));
using u32x2  = unsigned int __attribute__((ext_vector_type(2)));
using u32x4  = unsigned int __attribute__((ext_vector_type(4)));

#define L_SEQ  2048
#define DMODEL 2048
#define NQH    32
#define NKVH   8
#define HDIM   64
#define QKV_N  3072   // NQH*HDIM + 2*NKVH*HDIM

// fragment-ordered K/V: per kv-head, 64 key-blocks of 32; each block = 4 frags
// of (64 lanes x 8 elems) = 2048 elems; per-head stride:
#define KVF_HSTRIDE (64 * 4 * 64 * 8)   // 131072 elems = 256 KiB

// ---------- helpers ----------
__device__ __forceinline__ void gload_lds16(const void* g, void* lds) {
  __builtin_amdgcn_global_load_lds((__attribute__((address_space(1))) void*)(g),
                                   (__attribute__((address_space(3))) void*)(lds),
                                   16, 0, 0);
}

__device__ __forceinline__ unsigned pack2(float a, float b) {
  union { bf16 h[2]; unsigned u; } x;
  x.h[0] = (bf16)a; x.h[1] = (bf16)b;
  return x.u;
}

// ---------- fp32 -> bf16 convert ----------
__global__ void cvt_f32_bf16(const float* __restrict__ in, bf16* __restrict__ out, long n) {
  const long stride = (long)gridDim.x * blockDim.x;
  const long n4 = n >> 2;
  for (long i = (long)blockIdx.x * blockDim.x + threadIdx.x; i < n4; i += stride) {
    const float4 v = reinterpret_cast<const float4*>(in)[i];
    bf16x4 o = { (bf16)v.x, (bf16)v.y, (bf16)v.z, (bf16)v.w };
    reinterpret_cast<bf16x4*>(out)[i] = o;
  }
}

// ---------- bf16 GEMM: C(MxN) = A(MxK) * B(NxK)^T, 128x64 tile, BK=64 ----------
// 2-phase double-buffered; 4 waves in 2x2, wave computes 64x32.
// Grid: (N/64, M/128) -> 768 / 512 blocks (3 / 2 per CU).
template <typename OutT>
__global__ __launch_bounds__(256)
void gemm_bt(const bf16* __restrict__ A, const bf16* __restrict__ B,
             OutT* __restrict__ C, int M, int N, int K) {
  __shared__ bf16 As[2][128 * 64];
  __shared__ bf16 Bs[2][64 * 64];
  const int tid = threadIdx.x;
  const int w = tid >> 6, l = tid & 63;
  const int wr = w >> 1, wc = w & 1;
  const int lq = l & 15, lg = l >> 4;
  const long m0 = (long)blockIdx.y * 128;
  const long n0 = (long)blockIdx.x * 64;

  const int lrow = l >> 3;
  const int scol = ((l & 7) ^ lrow) << 3;   // swizzled element column within BK

  f32x4 acc[4][2];
#pragma unroll
  for (int i = 0; i < 4; ++i)
#pragma unroll
    for (int j = 0; j < 2; ++j) acc[i][j] = f32x4{0.f, 0.f, 0.f, 0.f};

  // prologue: stage tile 0 into buf 0
#pragma unroll
  for (int i = 0; i < 4; ++i) {
    const int r0 = (w * 4 + i) * 8;
    gload_lds16(A + (m0 + r0 + lrow) * (long)K + scol, &As[0][r0 * 64]);
  }
#pragma unroll
  for (int i = 0; i < 2; ++i) {
    const int r0 = (w * 2 + i) * 8;
    gload_lds16(B + (n0 + r0 + lrow) * (long)K + scol, &Bs[0][r0 * 64]);
  }
  __syncthreads();

  const int nk = K >> 6;
  for (int t = 0; t < nk; ++t) {
    const int cur = t & 1, nxt = cur ^ 1;
    const int k1 = (t + 1 < nk) ? (t + 1) * 64 : t * 64;
#pragma unroll
    for (int i = 0; i < 4; ++i) {
      const int r0 = (w * 4 + i) * 8;
      gload_lds16(A + (m0 + r0 + lrow) * (long)K + k1 + scol, &As[nxt][r0 * 64]);
    }
#pragma unroll
    for (int i = 0; i < 2; ++i) {
      const int r0 = (w * 2 + i) * 8;
      gload_lds16(B + (n0 + r0 + lrow) * (long)K + k1 + scol, &Bs[nxt][r0 * 64]);
    }
    // compute current tile while next-tile loads are in flight
#pragma unroll
    for (int kk = 0; kk < 2; ++kk) {
      bf16x8 af[4], bfr[2];
#pragma unroll
      for (int tt = 0; tt < 4; ++tt) {
        const int rowA = wr * 64 + tt * 16 + lq;
        const int blkA = (kk * 4 + lg) ^ (rowA & 7);
        af[tt] = *reinterpret_cast<const bf16x8*>(&As[cur][rowA * 64 + blkA * 8]);
      }
#pragma unroll
      for (int tt = 0; tt < 2; ++tt) {
        const int rowB = wc * 32 + tt * 16 + lq;
        const int blkB = (kk * 4 + lg) ^ (rowB & 7);
        bfr[tt] = *reinterpret_cast<const bf16x8*>(&Bs[cur][rowB * 64 + blkB * 8]);
      }
#pragma unroll
      for (int mt = 0; mt < 4; ++mt)
#pragma unroll
        for (int nt = 0; nt < 2; ++nt)
          acc[mt][nt] = __builtin_amdgcn_mfma_f32_16x16x32_bf16(af[mt], bfr[nt], acc[mt][nt], 0, 0, 0);
    }
    __syncthreads();
  }

#pragma unroll
  for (int mt = 0; mt < 4; ++mt)
#pragma unroll
    for (int r = 0; r < 4; ++r) {
      const long row = m0 + wr * 64 + mt * 16 + lg * 4 + r;
#pragma unroll
      for (int nt = 0; nt < 2; ++nt) {
        const long col = n0 + wc * 32 + nt * 16 + lq;
        C[row * (long)N + col] = (OutT)acc[mt][nt][r];
      }
    }
}

// ---------- RoPE + RMSNorm for Q and K ----------
// Q scaled by SCALE*log2(e); K written directly in MFMA-fragment order.
__global__ __launch_bounds__(256)
void rope_rms(const bf16* __restrict__ qkv, const float* __restrict__ qg,
              const float* __restrict__ kg, bf16* __restrict__ qo, bf16* __restrict__ kfr) {
  const int gid = blockIdx.x * 4 + (threadIdx.x >> 6);
  const int lane = threadIdx.x & 63;
  const int pos = gid / 40;
  const int hh = gid % 40;            // 0..31 q heads, 32..39 k heads
  const bool isq = hh < 32;
  const int col = isq ? hh * HDIM : NQH * HDIM + (hh - 32) * HDIM;

  float x = (float)qkv[(long)pos * QKV_N + col + lane];
  float p = __shfl_xor(x, 1);
  const float fi = (float)(lane & ~1) * (1.0f / 64.0f);
  const float inv = powf(50000.0f, -fi);
  const float ang = (float)pos * inv;
  const float sn = sinf(ang), cs = cosf(ang);
  const float r = (lane & 1) ? (p * sn + x * cs) : (x * cs - p * sn);

  float ss = r * r;
#pragma unroll
  for (int off = 1; off < 64; off <<= 1) ss += __shfl_xor(ss, off);
  const float scl = rsqrtf(ss * (1.0f / 64.0f) + 1e-5f);
  const float g = isq ? qg[lane] : kg[lane];
  const float o = r * scl * g;

  if (isq) {
    qo[(long)pos * DMODEL + hh * HDIM + lane] = (bf16)(o * 0.18033688011112042f);
  } else {
    // frag order: element (pos, d) -> lane' = (pos&31) + 32*((d>>3)&1),
    // c = d>>4, e = d&7, kb = pos>>5
    const int kvh = hh - 32;
    const int d = lane;
    const int lp = (pos & 31) + (((d >> 3) & 1) << 5);
    const long idx = ((((long)kvh * 64 + (pos >> 5)) * 4 + (d >> 4)) * 64 + lp) * 8 + (d & 7);
    kfr[idx] = (bf16)o;
  }
}

// ---------- V repack: qkv cols [2560,3072) -> vfr in MFMA-fragment order ----------
// frag f = s*2+dh holds V[pos = kb*32 + s*16 + (l>>5)*8 + e][d = dh*32 + (l&31)]
__global__ __launch_bounds__(256)
void repack_v(const bf16* __restrict__ qkv, bf16* __restrict__ vfr) {
  __shared__ bf16 t[32][72];
  const int kvh = blockIdx.x >> 6;
  const int kb = blockIdx.x & 63;
  const int tid = threadIdx.x;

  // stage 32 pos x 64 d tile (coalesced 16B loads)
  {
    const int row = tid >> 3;
    const int cc = (tid & 7) * 8;
    const bf16* g = qkv + (long)(kb * 32 + row) * QKV_N + (NQH * HDIM + NKVH * HDIM) + kvh * HDIM + cc;
    *reinterpret_cast<u32x4*>(&t[row][cc]) = *reinterpret_cast<const u32x4*>(g);
  }
  __syncthreads();

  const int f = tid >> 6, l = tid & 63;
  const int s = f >> 1, dh = f & 1;
  const int hi = l >> 5, l31 = l & 31;
  union { bf16 b[8]; u32x4 u; } o;
#pragma unroll
  for (int e = 0; e < 8; ++e) o.b[e] = t[s * 16 + hi * 8 + e][dh * 32 + l31];
  bf16* od = vfr + (((long)(kvh * 64 + kb) * 4 + f) * 64 + l) * 8;
  *reinterpret_cast<u32x4*>(od) = o.u;
}

// ---------- flash attention (causal, GQA), wave-independent, no LDS ----------
// Per wave: 32 q-rows of one head; K/V read from fragment-ordered buffers
// (lane-linear 16B loads, fully coalesced). Swapped MFMAs keep q lane-local.
__global__ __launch_bounds__(256)
void flash_attn(const bf16* __restrict__ Q, const bf16* __restrict__ Kfr,
                const bf16* __restrict__ Vfr, bf16* __restrict__ Og) {
  const int w = threadIdx.x >> 6, l = threadIdx.x & 63;
  const int lane31 = l & 31, hi = l >> 5;
  const int wg = blockIdx.x * 4 + w;
  const int h = wg & 31;                 // 4 heads per block share kvh + key range
  const int qi = 63 - (wg >> 5);         // heavy q-tiles dispatched first
  const int kvh = h >> 2;
  const int q0 = qi * 32;
  const int q_abs = q0 + lane31;
  const int l8 = l * 8;

  // Q fragments (B-frag of ST): lane -> Q[q0+lane31][c*16 + hi*8 + e]
  const bf16* qrow = Q + (long)q_abs * DMODEL + h * HDIM + hi * 8;
  bf16x8 qf[4];
#pragma unroll
  for (int c = 0; c < 4; ++c) qf[c] = *reinterpret_cast<const bf16x8*>(qrow + c * 16);

  f32x16 o0, o1;
#pragma unroll
  for (int r = 0; r < 16; ++r) { o0[r] = 0.f; o1[r] = 0.f; }
  float m = -3.0e38f, lsum = 0.f;

  const bf16* kfrh = Kfr + (long)kvh * KVF_HSTRIDE;
  const bf16* vfrh = Vfr + (long)kvh * KVF_HSTRIDE;

  const int nst = qi + 1;                // 32-key subtiles

  // prologue: K fragments for subtile 0 (lane-linear, coalesced)
  bf16x8 kc0, kc1, kc2, kc3;
  {
    const bf16* kp = kfrh + l8;
    kc0 = *reinterpret_cast<const bf16x8*>(kp);
    kc1 = *reinterpret_cast<const bf16x8*>(kp + 512);
    kc2 = *reinterpret_cast<const bf16x8*>(kp + 1024);
    kc3 = *reinterpret_cast<const bf16x8*>(kp + 1536);
  }

  for (int sti = 0; sti < nst; ++sti) {
    const int kb0 = sti * 32;

    // V loads for THIS iter issued early (consumed after softmax)
    const bf16* vp = vfrh + (long)sti * 2048 + l8;
    const bf16x8 va0 = *reinterpret_cast<const bf16x8*>(vp);          // f=0: s0,d0-31
    const bf16x8 vb0 = *reinterpret_cast<const bf16x8*>(vp + 512);    // f=1: s0,d32-63
    const bf16x8 va1 = *reinterpret_cast<const bf16x8*>(vp + 1024);   // f=2: s1,d0-31
    const bf16x8 vb1 = *reinterpret_cast<const bf16x8*>(vp + 1536);   // f=3: s1,d32-63

    // NEXT iter's K loads (clamped, branchless)
    const long knoff = (sti + 1 < nst) ? (long)(sti + 1) * 2048 : 0;
    const bf16* kp = kfrh + knoff + l8;
    const bf16x8 kn0 = *reinterpret_cast<const bf16x8*>(kp);
    const bf16x8 kn1 = *reinterpret_cast<const bf16x8*>(kp + 512);
    const bf16x8 kn2 = *reinterpret_cast<const bf16x8*>(kp + 1024);
    const bf16x8 kn3 = *reinterpret_cast<const bf16x8*>(kp + 1536);

    // ---- ST = K * Q^T over 4 d-chunks ----
    f32x16 st;
#pragma unroll
    for (int r = 0; r < 16; ++r) st[r] = 0.f;
    st = __builtin_amdgcn_mfma_f32_32x32x16_bf16(kc0, qf[0], st, 0, 0, 0);
    st = __builtin_amdgcn_mfma_f32_32x32x16_bf16(kc1, qf[1], st, 0, 0, 0);
    st = __builtin_amdgcn_mfma_f32_32x32x16_bf16(kc2, qf[2], st, 0, 0, 0);
    st = __builtin_amdgcn_mfma_f32_32x32x16_bf16(kc3, qf[3], st, 0, 0, 0);

    // ---- causal mask (diagonal region only) ----
    if (kb0 + 31 > q0) {
#pragma unroll
      for (int r = 0; r < 16; ++r) {
        const int k_abs = kb0 + (r & 3) + 8 * (r >> 2) + 4 * hi;
        if (k_abs > q_abs) st[r] = -3.0e38f;
      }
    }

    // ---- online softmax (base-2 domain; scale folded into Q) ----
    float mx = st[0];
#pragma unroll
    for (int r = 1; r < 16; ++r) mx = fmaxf(mx, st[r]);
    mx = fmaxf(mx, __shfl_xor(mx, 32));
    if (!__all(mx - m <= 8.0f)) {        // defer-max, THR=8
      const float mn = fmaxf(m, mx);
      const float al = __builtin_amdgcn_exp2f(m - mn);
      m = mn; lsum *= al;
#pragma unroll
      for (int r = 0; r < 16; ++r) { o0[r] *= al; o1[r] *= al; }
    }
    float p[16];
    float rs = 0.f;
#pragma unroll
    for (int r = 0; r < 16; ++r) { p[r] = __builtin_amdgcn_exp2f(st[r] - m); rs += p[r]; }
    rs += __shfl_xor(rs, 32);
    lsum += rs;

    // ---- PV: assemble P B-frags in-register (permlane32_swap), 2 k-slices ----
#pragma unroll
    for (int s = 0; s < 2; ++s) {
      const int j = s * 8;
      const unsigned W0 = pack2(p[j + 0], p[j + 1]);
      const unsigned W1 = pack2(p[j + 2], p[j + 3]);
      const unsigned W2 = pack2(p[j + 4], p[j + 5]);
      const unsigned W3 = pack2(p[j + 6], p[j + 7]);
      u32x4 pw;
#if __has_builtin(__builtin_amdgcn_permlane32_swap)
      {
        using i32x2 = int __attribute__((ext_vector_type(2)));
        const i32x2 r02 = __builtin_amdgcn_permlane32_swap((int)W0, (int)W2, false, false);
        const i32x2 r13 = __builtin_amdgcn_permlane32_swap((int)W1, (int)W3, false, false);
        pw = u32x4{ (unsigned)r02[0], (unsigned)r13[0], (unsigned)r02[1], (unsigned)r13[1] };
      }
#else
      {
        const unsigned X0 = (unsigned)__shfl_xor((int)W0, 32);
        const unsigned X1 = (unsigned)__shfl_xor((int)W1, 32);
        const unsigned X2 = (unsigned)__shfl_xor((int)W2, 32);
        const unsigned X3 = (unsigned)__shfl_xor((int)W3, 32);
        pw = u32x4{ hi ? X2 : W0, hi ? X3 : W1, hi ? W2 : X0, hi ? W3 : X1 };
      }
#endif
      const bf16x8 pf = __builtin_bit_cast(bf16x8, pw);
      if (s == 0) {
        o0 = __builtin_amdgcn_mfma_f32_32x32x16_bf16(va0, pf, o0, 0, 0, 0);
        o1 = __builtin_amdgcn_mfma_f32_32x32x16_bf16(vb0, pf, o1, 0, 0, 0);
      } else {
        o0 = __builtin_amdgcn_mfma_f32_32x32x16_bf16(va1, pf, o0, 0, 0, 0);
        o1 = __builtin_amdgcn_mfma_f32_32x32x16_bf16(vb1, pf, o1, 0, 0, 0);
      }
    }

    kc0 = kn0; kc1 = kn1; kc2 = kn2; kc3 = kn3;
  }

  // ---- normalize + store: lane owns q-row, regs span d ----
  const float rl = 1.0f / lsum;
  bf16* orow = Og + (long)q_abs * DMODEL + h * HDIM;
#pragma unroll
  for (int g = 0; g < 4; ++g) {
    const int d0 = 8 * g + 4 * hi;
    u32x2 s0 = { pack2(o0[4 * g + 0] * rl, o0[4 * g + 1] * rl),
                 pack2(o0[4 * g + 2] * rl, o0[4 * g + 3] * rl) };
    u32x2 s1 = { pack2(o1[4 * g + 0] * rl, o1[4 * g + 1] * rl),
                 pack2(o1[4 * g + 2] * rl, o1[4 * g + 3] * rl) };
    *reinterpret_cast<u32x2*>(orow + d0) = s0;
    *reinterpret_cast<u32x2*>(orow + 32 + d0) = s1;
  }
}

// ---------- launch ----------
extern "C" void kernel_launch(void* const* d_in, const int* in_sizes, int n_in,
                              void* d_out, int out_size, void* d_ws, size_t ws_size,
                              hipStream_t stream) {
  const float* x       = (const float*)d_in[0];
  const float* w_qkv   = (const float*)d_in[1];
  const float* w_out   = (const float*)d_in[2];
  const float* q_gamma = (const float*)d_in[3];
  const float* k_gamma = (const float*)d_in[4];
  // d_in[5] = mask (causal tril) — implemented analytically.

  char* ws = (char*)d_ws;
  bf16* xb  = (bf16*)(ws);                       //  8 MiB  x bf16
  bf16* wqb = (bf16*)(ws + (8ul  << 20));        // 12 MiB  w_qkv bf16
  bf16* wob = (bf16*)(ws + (20ul << 20));        //  8 MiB  w_out bf16
  bf16* qkv = (bf16*)(ws + (28ul << 20));        // 12 MiB  qkv bf16
  bf16* qb  = (bf16*)(ws + (40ul << 20));        //  8 MiB  roped/normed Q (pre-scaled)
  bf16* kfr = (bf16*)(ws + (48ul << 20));        //  2 MiB  roped/normed K, frag order
  bf16* vfr = (bf16*)(ws + (50ul << 20));        //  2 MiB  V, frag order
  bf16* ao  = (bf16*)(ws + (52ul << 20));        //  8 MiB  attention out
  float* out = (float*)d_out;

  cvt_f32_bf16<<<2048, 256, 0, stream>>>(x, xb, (long)L_SEQ * DMODEL);
  cvt_f32_bf16<<<2048, 256, 0, stream>>>(w_qkv, wqb, (long)QKV_N * DMODEL);
  cvt_f32_bf16<<<2048, 256, 0, stream>>>(w_out, wob, (long)DMODEL * DMODEL);

  gemm_bt<bf16><<<dim3(QKV_N / 64, L_SEQ / 128), 256, 0, stream>>>(xb, wqb, qkv, L_SEQ, QKV_N, DMODEL);

  rope_rms<<<(L_SEQ * 40) / 4, 256, 0, stream>>>(qkv, q_gamma, k_gamma, qb, kfr);
  repack_v<<<NKVH * (L_SEQ / 32), 256, 0, stream>>>(qkv, vfr);

  flash_attn<<<(NQH * (L_SEQ / 32)) / 4, 256, 0, stream>>>(qb, kfr, vfr, ao);

  gemm_bt<float><<<dim3(DMODEL / 64, L_SEQ / 128), 256, 0, stream>>>(ao, wob, out, L_SEQ, DMODEL, DMODEL);
}

// Round 5
// 171.732 us; speedup vs baseline: 1.3065x; 1.0361x over previous
//
#include <hip/hip_runtime.h>

using bf16   = __bf16;
using bf16x4 = __bf16 __attribute__((ext_vector_type(4)));
using bf16x8 = __bf16 __attribute__((ext_vector_type(8)));
using f32x4  = float __attribute__((ext_vector_type(4)));
using f32x16 = float __attribute__((ext_vector_type(16)));
using u32x2  = unsigned int __attribute__((ext_vector_type(2)));
using u32x4  = unsigned int __attribute__((ext_vector_type(4)));

#define L_SEQ  2048
#define DMODEL 2048
#define NQH    32
#define NKVH   8
#define HDIM   64
#define QKV_N  3072   // NQH*HDIM + 2*NKVH*HDIM

// fragment-ordered K/V: per kv-head, 64 key-blocks of 32; each block = 4 frags
// of (64 lanes x 8 elems) = 2048 elems; per-head stride:
#define KVF_HSTRIDE (64 * 4 * 64 * 8)   // 131072 elems = 256 KiB

// ---------- helpers ----------
__device__ __forceinline__ void gload_lds16(const void* g, void* lds) {
  __builtin_amdgcn_global_load_lds((__attribute__((address_space(1))) void*)(g),
                                   (__attribute__((address_space(3))) void*)(lds),
                                   16, 0, 0);
}

__device__ __forceinline__ unsigned pack2(float a, float b) {
  union { bf16 h[2]; unsigned u; } x;
  x.h[0] = (bf16)a; x.h[1] = (bf16)b;
  return x.u;
}

// ---------- fp32 -> bf16 convert ----------
__global__ void cvt_f32_bf16(const float* __restrict__ in, bf16* __restrict__ out, long n) {
  const long stride = (long)gridDim.x * blockDim.x;
  const long n4 = n >> 2;
  for (long i = (long)blockIdx.x * blockDim.x + threadIdx.x; i < n4; i += stride) {
    const float4 v = reinterpret_cast<const float4*>(in)[i];
    bf16x4 o = { (bf16)v.x, (bf16)v.y, (bf16)v.z, (bf16)v.w };
    reinterpret_cast<bf16x4*>(out)[i] = o;
  }
}

// ---------- bf16 GEMM: C(MxN) = A(MxK) * B(NxK)^T, 128x64 tile, BK=64 ----------
// 2 waves per block; each wave computes the FULL 64x64 half-tile (16 MFMA per
// kk-half, m97 MFMA:ds_read ratio). Single-buffered LDS (24 KiB -> 6 blocks/CU;
// barrier drain hidden by multi-block overlap, m114).
// Grid: (N/64, M/128) -> QKV 768, out 512 blocks.
template <typename OutT>
__global__ __launch_bounds__(128)
void gemm_bt(const bf16* __restrict__ A, const bf16* __restrict__ B,
             OutT* __restrict__ C, int M, int N, int K) {
  __shared__ bf16 As[128 * 64];
  __shared__ bf16 Bs[64 * 64];
  const int tid = threadIdx.x;
  const int w = tid >> 6, l = tid & 63;
  const int lq = l & 15, lg = l >> 4;
  const long m0 = (long)blockIdx.y * 128;
  const long n0 = (long)blockIdx.x * 64;

  const int lrow = l >> 3;                   // row within 8-row group (0..7)
  const int scol = ((l & 7) ^ lrow) << 3;    // pre-swizzled global element column

  f32x4 acc[4][4];
#pragma unroll
  for (int i = 0; i < 4; ++i)
#pragma unroll
    for (int j = 0; j < 4; ++j) acc[i][j] = f32x4{0.f, 0.f, 0.f, 0.f};

  for (int k0 = 0; k0 < K; k0 += 64) {
    // stage A (128 rows): 8 passes x 2 waves x 8 rows
#pragma unroll
    for (int i = 0; i < 8; ++i) {
      const int r0 = (i * 2 + w) * 8;
      gload_lds16(A + (m0 + r0 + lrow) * (long)K + k0 + scol, &As[r0 * 64]);
    }
    // stage B (64 rows): 4 passes x 2 waves x 8 rows
#pragma unroll
    for (int i = 0; i < 4; ++i) {
      const int r0 = (i * 2 + w) * 8;
      gload_lds16(B + (n0 + r0 + lrow) * (long)K + k0 + scol, &Bs[r0 * 64]);
    }
    __syncthreads();
#pragma unroll
    for (int kk = 0; kk < 2; ++kk) {
      bf16x8 af[4], bfr[4];
#pragma unroll
      for (int t = 0; t < 4; ++t) {
        const int rowA = w * 64 + t * 16 + lq;
        const int blkA = (kk * 4 + lg) ^ (rowA & 7);
        af[t] = *reinterpret_cast<const bf16x8*>(&As[rowA * 64 + blkA * 8]);
        const int rowB = t * 16 + lq;
        const int blkB = (kk * 4 + lg) ^ (rowB & 7);
        bfr[t] = *reinterpret_cast<const bf16x8*>(&Bs[rowB * 64 + blkB * 8]);
      }
#pragma unroll
      for (int mt = 0; mt < 4; ++mt)
#pragma unroll
        for (int nt = 0; nt < 4; ++nt)
          acc[mt][nt] = __builtin_amdgcn_mfma_f32_16x16x32_bf16(af[mt], bfr[nt], acc[mt][nt], 0, 0, 0);
    }
    __syncthreads();
  }

#pragma unroll
  for (int mt = 0; mt < 4; ++mt)
#pragma unroll
    for (int r = 0; r < 4; ++r) {
      const long row = m0 + w * 64 + mt * 16 + lg * 4 + r;
#pragma unroll
      for (int nt = 0; nt < 4; ++nt) {
        const long col = n0 + nt * 16 + lq;
        C[row * (long)N + col] = (OutT)acc[mt][nt][r];
      }
    }
}

// ---------- RoPE + RMSNorm for Q and K ----------
// Q scaled by SCALE*log2(e); K written directly in MFMA-fragment order.
__global__ __launch_bounds__(256)
void rope_rms(const bf16* __restrict__ qkv, const float* __restrict__ qg,
              const float* __restrict__ kg, bf16* __restrict__ qo, bf16* __restrict__ kfr) {
  const int gid = blockIdx.x * 4 + (threadIdx.x >> 6);
  const int lane = threadIdx.x & 63;
  const int pos = gid / 40;
  const int hh = gid % 40;            // 0..31 q heads, 32..39 k heads
  const bool isq = hh < 32;
  const int col = isq ? hh * HDIM : NQH * HDIM + (hh - 32) * HDIM;

  float x = (float)qkv[(long)pos * QKV_N + col + lane];
  float p = __shfl_xor(x, 1);
  const float fi = (float)(lane & ~1) * (1.0f / 64.0f);
  const float inv = powf(50000.0f, -fi);
  const float ang = (float)pos * inv;
  const float sn = sinf(ang), cs = cosf(ang);
  const float r = (lane & 1) ? (p * sn + x * cs) : (x * cs - p * sn);

  float ss = r * r;
#pragma unroll
  for (int off = 1; off < 64; off <<= 1) ss += __shfl_xor(ss, off);
  const float scl = rsqrtf(ss * (1.0f / 64.0f) + 1e-5f);
  const float g = isq ? qg[lane] : kg[lane];
  const float o = r * scl * g;

  if (isq) {
    qo[(long)pos * DMODEL + hh * HDIM + lane] = (bf16)(o * 0.18033688011112042f);
  } else {
    // frag order: element (pos, d) -> lane' = (pos&31) + 32*((d>>3)&1),
    // c = d>>4, e = d&7, kb = pos>>5
    const int kvh = hh - 32;
    const int d = lane;
    const int lp = (pos & 31) + (((d >> 3) & 1) << 5);
    const long idx = ((((long)kvh * 64 + (pos >> 5)) * 4 + (d >> 4)) * 64 + lp) * 8 + (d & 7);
    kfr[idx] = (bf16)o;
  }
}

// ---------- V repack: qkv cols [2560,3072) -> vfr in MFMA-fragment order ----------
// frag f = s*2+dh holds V[pos = kb*32 + s*16 + (l>>5)*8 + e][d = dh*32 + (l&31)]
__global__ __launch_bounds__(256)
void repack_v(const bf16* __restrict__ qkv, bf16* __restrict__ vfr) {
  __shared__ bf16 t[32][72];
  const int kvh = blockIdx.x >> 6;
  const int kb = blockIdx.x & 63;
  const int tid = threadIdx.x;

  // stage 32 pos x 64 d tile (coalesced 16B loads)
  {
    const int row = tid >> 3;
    const int cc = (tid & 7) * 8;
    const bf16* g = qkv + (long)(kb * 32 + row) * QKV_N + (NQH * HDIM + NKVH * HDIM) + kvh * HDIM + cc;
    *reinterpret_cast<u32x4*>(&t[row][cc]) = *reinterpret_cast<const u32x4*>(g);
  }
  __syncthreads();

  const int f = tid >> 6, l = tid & 63;
  const int s = f >> 1, dh = f & 1;
  const int hi = l >> 5, l31 = l & 31;
  union { bf16 b[8]; u32x4 u; } o;
#pragma unroll
  for (int e = 0; e < 8; ++e) o.b[e] = t[s * 16 + hi * 8 + e][dh * 32 + l31];
  bf16* od = vfr + (((long)(kvh * 64 + kb) * 4 + f) * 64 + l) * 8;
  *reinterpret_cast<u32x4*>(od) = o.u;
}

// ---------- flash attention (causal, GQA), wave-independent, no LDS ----------
// Per wave: 32 q-rows of one head; K/V read from fragment-ordered buffers
// (lane-linear 16B loads, fully coalesced). Swapped MFMAs keep q lane-local.
__global__ __launch_bounds__(256)
void flash_attn(const bf16* __restrict__ Q, const bf16* __restrict__ Kfr,
                const bf16* __restrict__ Vfr, bf16* __restrict__ Og) {
  const int w = threadIdx.x >> 6, l = threadIdx.x & 63;
  const int lane31 = l & 31, hi = l >> 5;
  const int wg = blockIdx.x * 4 + w;
  const int h = wg & 31;                 // 4 heads per block share kvh + key range
  const int qi = 63 - (wg >> 5);         // heavy q-tiles dispatched first
  const int kvh = h >> 2;
  const int q0 = qi * 32;
  const int q_abs = q0 + lane31;
  const int l8 = l * 8;

  // Q fragments (B-frag of ST): lane -> Q[q0+lane31][c*16 + hi*8 + e]
  const bf16* qrow = Q + (long)q_abs * DMODEL + h * HDIM + hi * 8;
  bf16x8 qf[4];
#pragma unroll
  for (int c = 0; c < 4; ++c) qf[c] = *reinterpret_cast<const bf16x8*>(qrow + c * 16);

  f32x16 o0, o1;
#pragma unroll
  for (int r = 0; r < 16; ++r) { o0[r] = 0.f; o1[r] = 0.f; }
  float m = -3.0e38f, lsum = 0.f;

  const bf16* kfrh = Kfr + (long)kvh * KVF_HSTRIDE;
  const bf16* vfrh = Vfr + (long)kvh * KVF_HSTRIDE;

  const int nst = qi + 1;                // 32-key subtiles

  // prologue: K fragments for subtile 0 (lane-linear, coalesced)
  bf16x8 kc0, kc1, kc2, kc3;
  {
    const bf16* kp = kfrh + l8;
    kc0 = *reinterpret_cast<const bf16x8*>(kp);
    kc1 = *reinterpret_cast<const bf16x8*>(kp + 512);
    kc2 = *reinterpret_cast<const bf16x8*>(kp + 1024);
    kc3 = *reinterpret_cast<const bf16x8*>(kp + 1536);
  }

  for (int sti = 0; sti < nst; ++sti) {
    const int kb0 = sti * 32;

    // V loads for THIS iter issued early (consumed after softmax)
    const bf16* vp = vfrh + (long)sti * 2048 + l8;
    const bf16x8 va0 = *reinterpret_cast<const bf16x8*>(vp);          // f=0: s0,d0-31
    const bf16x8 vb0 = *reinterpret_cast<const bf16x8*>(vp + 512);    // f=1: s0,d32-63
    const bf16x8 va1 = *reinterpret_cast<const bf16x8*>(vp + 1024);   // f=2: s1,d0-31
    const bf16x8 vb1 = *reinterpret_cast<const bf16x8*>(vp + 1536);   // f=3: s1,d32-63

    // NEXT iter's K loads (clamped, branchless)
    const long knoff = (sti + 1 < nst) ? (long)(sti + 1) * 2048 : 0;
    const bf16* kp = kfrh + knoff + l8;
    const bf16x8 kn0 = *reinterpret_cast<const bf16x8*>(kp);
    const bf16x8 kn1 = *reinterpret_cast<const bf16x8*>(kp + 512);
    const bf16x8 kn2 = *reinterpret_cast<const bf16x8*>(kp + 1024);
    const bf16x8 kn3 = *reinterpret_cast<const bf16x8*>(kp + 1536);

    // ---- ST = K * Q^T over 4 d-chunks ----
    f32x16 st;
#pragma unroll
    for (int r = 0; r < 16; ++r) st[r] = 0.f;
    __builtin_amdgcn_s_setprio(1);
    st = __builtin_amdgcn_mfma_f32_32x32x16_bf16(kc0, qf[0], st, 0, 0, 0);
    st = __builtin_amdgcn_mfma_f32_32x32x16_bf16(kc1, qf[1], st, 0, 0, 0);
    st = __builtin_amdgcn_mfma_f32_32x32x16_bf16(kc2, qf[2], st, 0, 0, 0);
    st = __builtin_amdgcn_mfma_f32_32x32x16_bf16(kc3, qf[3], st, 0, 0, 0);
    __builtin_amdgcn_s_setprio(0);

    // ---- causal mask (diagonal region only) ----
    if (kb0 + 31 > q0) {
#pragma unroll
      for (int r = 0; r < 16; ++r) {
        const int k_abs = kb0 + (r & 3) + 8 * (r >> 2) + 4 * hi;
        if (k_abs > q_abs) st[r] = -3.0e38f;
      }
    }

    // ---- online softmax (base-2 domain; scale folded into Q) ----
    float mx = st[0];
#pragma unroll
    for (int r = 1; r < 16; ++r) mx = fmaxf(mx, st[r]);
    mx = fmaxf(mx, __shfl_xor(mx, 32));
    if (!__all(mx - m <= 8.0f)) {        // defer-max, THR=8
      const float mn = fmaxf(m, mx);
      const float al = __builtin_amdgcn_exp2f(m - mn);
      m = mn; lsum *= al;
#pragma unroll
      for (int r = 0; r < 16; ++r) { o0[r] *= al; o1[r] *= al; }
    }
    float p[16];
    float rs = 0.f;
#pragma unroll
    for (int r = 0; r < 16; ++r) { p[r] = __builtin_amdgcn_exp2f(st[r] - m); rs += p[r]; }
    rs += __shfl_xor(rs, 32);
    lsum += rs;

    // ---- PV: assemble P B-frags in-register (permlane32_swap), 2 k-slices ----
#pragma unroll
    for (int s = 0; s < 2; ++s) {
      const int j = s * 8;
      const unsigned W0 = pack2(p[j + 0], p[j + 1]);
      const unsigned W1 = pack2(p[j + 2], p[j + 3]);
      const unsigned W2 = pack2(p[j + 4], p[j + 5]);
      const unsigned W3 = pack2(p[j + 6], p[j + 7]);
      u32x4 pw;
#if __has_builtin(__builtin_amdgcn_permlane32_swap)
      {
        using i32x2 = int __attribute__((ext_vector_type(2)));
        const i32x2 r02 = __builtin_amdgcn_permlane32_swap((int)W0, (int)W2, false, false);
        const i32x2 r13 = __builtin_amdgcn_permlane32_swap((int)W1, (int)W3, false, false);
        pw = u32x4{ (unsigned)r02[0], (unsigned)r13[0], (unsigned)r02[1], (unsigned)r13[1] };
      }
#else
      {
        const unsigned X0 = (unsigned)__shfl_xor((int)W0, 32);
        const unsigned X1 = (unsigned)__shfl_xor((int)W1, 32);
        const unsigned X2 = (unsigned)__shfl_xor((int)W2, 32);
        const unsigned X3 = (unsigned)__shfl_xor((int)W3, 32);
        pw = u32x4{ hi ? X2 : W0, hi ? X3 : W1, hi ? W2 : X0, hi ? W3 : X1 };
      }
#endif
      const bf16x8 pf = __builtin_bit_cast(bf16x8, pw);
      __builtin_amdgcn_s_setprio(1);
      if (s == 0) {
        o0 = __builtin_amdgcn_mfma_f32_32x32x16_bf16(va0, pf, o0, 0, 0, 0);
        o1 = __builtin_amdgcn_mfma_f32_32x32x16_bf16(vb0, pf, o1, 0, 0, 0);
      } else {
        o0 = __builtin_amdgcn_mfma_f32_32x32x16_bf16(va1, pf, o0, 0, 0, 0);
        o1 = __builtin_amdgcn_mfma_f32_32x32x16_bf16(vb1, pf, o1, 0, 0, 0);
      }
      __builtin_amdgcn_s_setprio(0);
    }

    kc0 = kn0; kc1 = kn1; kc2 = kn2; kc3 = kn3;
  }

  // ---- normalize + store: lane owns q-row, regs span d ----
  const float rl = 1.0f / lsum;
  bf16* orow = Og + (long)q_abs * DMODEL + h * HDIM;
#pragma unroll
  for (int g = 0; g < 4; ++g) {
    const int d0 = 8 * g + 4 * hi;
    u32x2 s0 = { pack2(o0[4 * g + 0] * rl, o0[4 * g + 1] * rl),
                 pack2(o0[4 * g + 2] * rl, o0[4 * g + 3] * rl) };
    u32x2 s1 = { pack2(o1[4 * g + 0] * rl, o1[4 * g + 1] * rl),
                 pack2(o1[4 * g + 2] * rl, o1[4 * g + 3] * rl) };
    *reinterpret_cast<u32x2*>(orow + d0) = s0;
    *reinterpret_cast<u32x2*>(orow + 32 + d0) = s1;
  }
}

// ---------- launch ----------
extern "C" void kernel_launch(void* const* d_in, const int* in_sizes, int n_in,
                              void* d_out, int out_size, void* d_ws, size_t ws_size,
                              hipStream_t stream) {
  const float* x       = (const float*)d_in[0];
  const float* w_qkv   = (const float*)d_in[1];
  const float* w_out   = (const float*)d_in[2];
  const float* q_gamma = (const float*)d_in[3];
  const float* k_gamma = (const float*)d_in[4];
  // d_in[5] = mask (causal tril) — implemented analytically.

  char* ws = (char*)d_ws;
  bf16* xb  = (bf16*)(ws);                       //  8 MiB  x bf16
  bf16* wqb = (bf16*)(ws + (8ul  << 20));        // 12 MiB  w_qkv bf16
  bf16* wob = (bf16*)(ws + (20ul << 20));        //  8 MiB  w_out bf16
  bf16* qkv = (bf16*)(ws + (28ul << 20));        // 12 MiB  qkv bf16
  bf16* qb  = (bf16*)(ws + (40ul << 20));        //  8 MiB  roped/normed Q (pre-scaled)
  bf16* kfr = (bf16*)(ws + (48ul << 20));        //  2 MiB  roped/normed K, frag order
  bf16* vfr = (bf16*)(ws + (50ul << 20));        //  2 MiB  V, frag order
  bf16* ao  = (bf16*)(ws + (52ul << 20));        //  8 MiB  attention out
  float* out = (float*)d_out;

  cvt_f32_bf16<<<2048, 256, 0, stream>>>(x, xb, (long)L_SEQ * DMODEL);
  cvt_f32_bf16<<<2048, 256, 0, stream>>>(w_qkv, wqb, (long)QKV_N * DMODEL);
  cvt_f32_bf16<<<2048, 256, 0, stream>>>(w_out, wob, (long)DMODEL * DMODEL);

  gemm_bt<bf16><<<dim3(QKV_N / 64, L_SEQ / 128), 128, 0, stream>>>(xb, wqb, qkv, L_SEQ, QKV_N, DMODEL);

  rope_rms<<<(L_SEQ * 40) / 4, 256, 0, stream>>>(qkv, q_gamma, k_gamma, qb, kfr);
  repack_v<<<NKVH * (L_SEQ / 32), 256, 0, stream>>>(qkv, vfr);

  flash_attn<<<(NQH * (L_SEQ / 32)) / 4, 256, 0, stream>>>(qb, kfr, vfr, ao);

  gemm_bt<float><<<dim3(DMODEL / 64, L_SEQ / 128), 128, 0, stream>>>(ao, wob, out, L_SEQ, DMODEL, DMODEL);
}